// Round 1
// baseline (212.291 us; speedup 1.0000x reference)
//
#include <hip/hip_runtime.h>
#include <math.h>

#define B 4
#define S 1024
#define D 256
#define H 6
#define HD 64
#define NE 3
#define HHD 384
#define ROWS (B*S)
#define MAXN 128

typedef __attribute__((ext_vector_type(8))) short bf8_t;
typedef __attribute__((ext_vector_type(4))) float f32x4;

__device__ __forceinline__ float leaky(float x){ return x > 0.f ? x : 0.2f*x; }

__device__ __forceinline__ unsigned short f2bf(float f){
    union { float f; unsigned int u; } v; v.f = f;
    unsigned int u = v.u;
    return (unsigned short)((u + 0x7FFFu + ((u >> 16) & 1u)) >> 16);
}
__device__ __forceinline__ float bf2f(unsigned short h){
    union { unsigned int u; float f; } v; v.u = ((unsigned int)h) << 16;
    return v.f;
}
__device__ __forceinline__ float blo(unsigned int u){
    union { unsigned int u; float f; } v; v.u = u << 16; return v.f;
}
__device__ __forceinline__ float bhi(unsigned int u){
    union { unsigned int u; float f; } v; v.u = u & 0xffff0000u; return v.f;
}
__device__ __forceinline__ float i2f(int t){
    union { int i; float f; } v; v.i = t; return v.f;
}
__device__ __forceinline__ int f2i(float f){
    union { float f; int i; } v; v.f = f; return v.i;
}

// ---------- block ranges for prep_misc ----------
#define PB_CONV   1024
#define PB_NBR    1024
#define PB_W1     1536
#define PB_W2     1536
#define PB_BW      256
#define PB_ZERO    177
#define PB_ROUTER 1024
#define PB_TOTAL  (PB_CONV + PB_NBR + PB_W1 + PB_W2 + PB_BW + PB_ZERO + PB_ROUTER)
#define NZERO     45088

// All independent prep tasks in one launch (block-range dispatch).
__global__ __launch_bounds__(256) void prep_misc_kernel(
        const float* __restrict__ feature, const float* __restrict__ adj,
        const float* __restrict__ main_W1, const float* __restrict__ dep_W1,
        const float* __restrict__ main_W2, const float* __restrict__ dep_W2,
        const float* __restrict__ blend_W, const float* __restrict__ router_W,
        const int* __restrict__ doc_p, const int* __restrict__ sect_p,
        unsigned short* __restrict__ featbf, short* __restrict__ nbr,
        int4* __restrict__ nbc, unsigned short* __restrict__ w1nk,
        unsigned short* __restrict__ w2nk, unsigned short* __restrict__ bwt,
        float* __restrict__ zbase, float* __restrict__ rmask)
{
    int blk = blockIdx.x, tid = threadIdx.x;
    if (blk < PB_CONV){
        int idx = blk*256 + tid;                       // < ROWS*D/4
        float4 v = ((const float4*)feature)[idx];
        ushort4 o;
        o.x = f2bf(v.x); o.y = f2bf(v.y); o.z = f2bf(v.z); o.w = f2bf(v.w);
        ((ushort4*)featbf)[idx] = o;
        return;
    }
    blk -= PB_CONV;
    if (blk < PB_NBR){
        int wave = tid >> 6, lane = tid & 63;
        int row = blk*4 + wave;
        int b1 = S - *sect_p - *doc_p;
        int b2 = S - *doc_p;
        const float* ar = adj + (size_t)row*S + lane*16;
        float a[16];
        #pragma unroll
        for (int q = 0; q < 4; q++){
            float4 v = ((const float4*)ar)[q];
            a[q*4+0] = v.x; a[q*4+1] = v.y; a[q*4+2] = v.z; a[q*4+3] = v.w;
        }
        int t0 = lane*16;
        int k = 0, c1 = 0, c2 = 0;
        #pragma unroll
        for (int i = 0; i < 16; i++){
            if (a[i] > 0.f){
                k++;
                int t = t0 + i;
                if (t < b1) c1++;
                if (t < b2) c2++;
            }
        }
        int inc = k;
        #pragma unroll
        for (int d = 1; d < 64; d <<= 1){
            int u = __shfl_up(inc, d);
            if (lane >= d) inc += u;
        }
        int off = inc - k;
        int total = __shfl(inc, 63);
        int o = row*MAXN + off;
        #pragma unroll
        for (int i = 0; i < 16; i++){
            if (a[i] > 0.f) nbr[o++] = (short)(t0 + i);
        }
        for (int d = 32; d; d >>= 1){
            c1 += __shfl_down(c1, d);
            c2 += __shfl_down(c2, d);
        }
        if (lane == 0) nbc[row] = make_int4(total, c1, c2, 0);
        return;
    }
    blk -= PB_NBR;
    if (blk < PB_W1){
        int e = blk / 384;
        int idx = (blk - e*384)*256 + tid;             // < HHD*D
        const float* src = (e == 0) ? main_W1 : dep_W1 + (size_t)(e-1)*H*D*HD;
        int n = idx >> 8, k = idx & 255;
        int h = n >> 6, o = n & 63;
        w1nk[(size_t)e*HHD*D + idx] = f2bf(src[(h*D + k)*HD + o]);
        return;
    }
    blk -= PB_W1;
    if (blk < PB_W2){
        int g = blk*256 + tid;                         // < 4*D*HHD
        int e = g / (D*HHD);
        int rem = g - e*(D*HHD);
        int n = rem / HHD, k = rem - n*HHD;
        const float* src = (e == 0) ? main_W2 : dep_W2 + (size_t)(e-1)*HHD*D;
        w2nk[g] = f2bf(src[k*D + n]);
        return;
    }
    blk -= PB_W2;
    if (blk < PB_BW){
        int col = blk, k = tid;
        bwt[col*D + k] = f2bf(blend_W[k*D + col]);
        return;
    }
    blk -= PB_BW;
    if (blk < PB_ZERO){
        int idx = blk*256 + tid;
        if (idx < NZERO) zbase[idx] = 0.f;
        return;
    }
    blk -= PB_ZERO;
    {
        int wave = tid >> 6, lane = tid & 63;
        int row = blk*4 + wave;
        float4 xv = ((const float4*)(feature + (size_t)row*D))[lane];
        int f = lane*4;
        float xa[4] = {xv.x, xv.y, xv.z, xv.w};
        float p0 = 0.f, p1 = 0.f, p2 = 0.f;
        #pragma unroll
        for (int j = 0; j < 4; j++){
            p0 += xa[j]*router_W[(f+j)*NE + 0];
            p1 += xa[j]*router_W[(f+j)*NE + 1];
            p2 += xa[j]*router_W[(f+j)*NE + 2];
        }
        for (int off = 32; off; off >>= 1){
            p0 += __shfl_down(p0, off);
            p1 += __shfl_down(p1, off);
            p2 += __shfl_down(p2, off);
        }
        if (lane == 0){
            float p[3] = {p0, p1, p2};
            int ex = 0;
            for (int e = 1; e < NE; e++) if (p[e] <= p[ex]) ex = e;
            for (int e = 0; e < NE; e++) rmask[e*ROWS + row] = (e == ex) ? 0.f : 1.f;
        }
    }
}

// ---------- GEMM1 (x@W1) + fused es/ed + colmean; 128-wide M-tile (2 heads/block) ----------
// grid (3, ROWS/64, 5). z<4: expert slices; z==4: blend gate (x<2).
__global__ __launch_bounds__(256, 4) void gemm1_kernel(const unsigned short* __restrict__ w1nk,
                                                    const unsigned short* __restrict__ featbf,
                                                    const float* __restrict__ rmask,
                                                    const float* __restrict__ main_a1s,
                                                    const float* __restrict__ main_a1d,
                                                    const float* __restrict__ dep_a1s,
                                                    const float* __restrict__ dep_a1d,
                                                    const unsigned short* __restrict__ bwt,
                                                    const float* __restrict__ bb,
                                                    unsigned short* __restrict__ htn4,
                                                    float* __restrict__ es8,
                                                    float* __restrict__ ed8,
                                                    float* __restrict__ meanV1p,
                                                    float* __restrict__ gatebuf,
                                                    float* __restrict__ sumBuf){
    __shared__ float ep[2][2][64][17];      // [head][s/d][n][m-chunk]
    int tid = threadIdx.x, wave = tid >> 6, lane = tid & 63;
    int quad = lane >> 4, l16 = lane & 15;
    int e = blockIdx.z;
    int n0 = blockIdx.y*64;
    f32x4 z4 = {0.f,0.f,0.f,0.f};
    bf8_t bz = {0,0,0,0,0,0,0,0};

    if (e == 4){
        // ---- blend gate GEMM: gate[row][col] = sigmoid(x@blend_W + b), 128-wide m ----
        if (blockIdx.x >= 2) return;
        int m0 = blockIdx.x*128;
        const unsigned short* arow0 = bwt + (size_t)(m0 + wave*16 + l16)*D + quad*8;
        const unsigned short* arow1 = arow0 + (size_t)64*D;
        const unsigned short* brow[4];
        #pragma unroll
        for (int j = 0; j < 4; j++)
            brow[j] = featbf + (size_t)(n0 + j*16 + l16)*D + quad*8;
        f32x4 acc[8] = {z4, z4, z4, z4, z4, z4, z4, z4};
        bf8_t a0F = *(const bf8_t*)(arow0);
        bf8_t a1F = *(const bf8_t*)(arow1);
        bf8_t bF[4];
        #pragma unroll
        for (int j = 0; j < 4; j++) bF[j] = *(const bf8_t*)(brow[j]);
        #pragma unroll
        for (int it = 0; it < D/32; it++){
            bf8_t a0C = a0F, a1C = a1F;
            bf8_t bC[4] = {bF[0], bF[1], bF[2], bF[3]};
            if (it + 1 < D/32){
                int kn = (it + 1)*32;
                a0F = *(const bf8_t*)(arow0 + kn);
                a1F = *(const bf8_t*)(arow1 + kn);
                #pragma unroll
                for (int j = 0; j < 4; j++) bF[j] = *(const bf8_t*)(brow[j] + kn);
            }
            #pragma unroll
            for (int j = 0; j < 4; j++){
                acc[j]   = __builtin_amdgcn_mfma_f32_16x16x32_bf16(a0C, bC[j], acc[j],   0, 0, 0);
                acc[4+j] = __builtin_amdgcn_mfma_f32_16x16x32_bf16(a1C, bC[j], acc[4+j], 0, 0, 0);
            }
        }
        int mbase0 = m0 + wave*16 + quad*4;
        int mbase1 = mbase0 + 64;
        float bias0[4], bias1[4];
        #pragma unroll
        for (int r = 0; r < 4; r++){ bias0[r] = bb[mbase0 + r]; bias1[r] = bb[mbase1 + r]; }
        float lsum = 0.f;
        #pragma unroll
        for (int j = 0; j < 4; j++){
            int rown = n0 + j*16 + l16;
            f32x4 st0, st1;
            #pragma unroll
            for (int r = 0; r < 4; r++){
                float g0 = 1.f/(1.f + __expf(-(acc[j][r] + bias0[r])));
                float g1 = 1.f/(1.f + __expf(-(acc[4+j][r] + bias1[r])));
                lsum += g0 + g1;
                st0[r] = g0; st1[r] = g1;
            }
            *(f32x4*)(gatebuf + (size_t)rown*D + mbase0) = st0;
            *(f32x4*)(gatebuf + (size_t)rown*D + mbase1) = st1;
        }
        float* redp = &ep[0][0][0][0];
        redp[tid] = lsum;
        __syncthreads();
        for (int sft = 128; sft; sft >>= 1){
            if (tid < sft) redp[tid] += redp[tid + sft];
            __syncthreads();
        }
        if (tid == 0) atomicAdd(sumBuf, redp[0]);
        return;
    }

    // ---- expert slice: head pair p -> heads 2p, 2p+1 ----
    int p = blockIdx.x;
    int m0 = p*128;
    const unsigned short* arow0 = w1nk + (size_t)e*HHD*D + (size_t)(m0 + wave*16 + l16)*D + quad*8;
    const unsigned short* arow1 = arow0 + (size_t)64*D;
    const unsigned short* brow[4];
    bool zr[4];
    #pragma unroll
    for (int j = 0; j < 4; j++){
        int n = n0 + j*16 + l16;
        brow[j] = featbf + (size_t)n*D + quad*8;
        zr[j] = (e > 0) ? (rmask[(size_t)(e-1)*ROWS + n] == 0.f) : false;
    }
    f32x4 acc[8] = {z4, z4, z4, z4, z4, z4, z4, z4};
    bf8_t a0F = *(const bf8_t*)(arow0);
    bf8_t a1F = *(const bf8_t*)(arow1);
    bf8_t bF[4];
    #pragma unroll
    for (int j = 0; j < 4; j++) bF[j] = zr[j] ? bz : *(const bf8_t*)(brow[j]);
    #pragma unroll
    for (int it = 0; it < D/32; it++){
        bf8_t a0C = a0F, a1C = a1F;
        bf8_t bC[4] = {bF[0], bF[1], bF[2], bF[3]};
        if (it + 1 < D/32){
            int kn = (it + 1)*32;
            a0F = *(const bf8_t*)(arow0 + kn);
            a1F = *(const bf8_t*)(arow1 + kn);
            #pragma unroll
            for (int j = 0; j < 4; j++) bF[j] = zr[j] ? bz : *(const bf8_t*)(brow[j] + kn);
        }
        #pragma unroll
        for (int j = 0; j < 4; j++){
            acc[j]   = __builtin_amdgcn_mfma_f32_16x16x32_bf16(a0C, bC[j], acc[j],   0, 0, 0);
            acc[4+j] = __builtin_amdgcn_mfma_f32_16x16x32_bf16(a1C, bC[j], acc[4+j], 0, 0, 0);
        }
    }
    int b = n0 >> 10;
    int mbase0 = m0 + wave*16 + quad*4;
    int mbase1 = mbase0 + 64;
    int obase = wave*16 + quad*4;   // o within head (0..63)
    int h0 = p*2, h1 = p*2 + 1;
    #pragma unroll
    for (int j = 0; j < 4; j++){
        int row = n0 + j*16 + l16;
        ushort4 o0, o1;
        o0.x = f2bf(acc[j][0]);   o0.y = f2bf(acc[j][1]);
        o0.z = f2bf(acc[j][2]);   o0.w = f2bf(acc[j][3]);
        o1.x = f2bf(acc[4+j][0]); o1.y = f2bf(acc[4+j][1]);
        o1.z = f2bf(acc[4+j][2]); o1.w = f2bf(acc[4+j][3]);
        *(ushort4*)(htn4 + ((size_t)e*ROWS + row)*HHD + mbase0) = o0;
        *(ushort4*)(htn4 + ((size_t)e*ROWS + row)*HHD + mbase1) = o1;
    }
    const float* a1sp = (e == 0) ? main_a1s : dep_a1s + (size_t)(e-1)*H*HD;
    const float* a1dp = (e == 0) ? main_a1d : dep_a1d + (size_t)(e-1)*H*HD;
    float s0v[4], d0v[4], s1v[4], d1v[4];
    #pragma unroll
    for (int r = 0; r < 4; r++){
        s0v[r] = a1sp[mbase0 + r]; d0v[r] = a1dp[mbase0 + r];
        s1v[r] = a1sp[mbase1 + r]; d1v[r] = a1dp[mbase1 + r];
    }
    #pragma unroll
    for (int j = 0; j < 4; j++){
        float ps0 = 0.f, pd0 = 0.f, ps1 = 0.f, pd1 = 0.f;
        #pragma unroll
        for (int r = 0; r < 4; r++){
            ps0 += acc[j][r]*s0v[r];   pd0 += acc[j][r]*d0v[r];
            ps1 += acc[4+j][r]*s1v[r]; pd1 += acc[4+j][r]*d1v[r];
        }
        ep[0][0][j*16 + l16][wave*4 + quad] = ps0;
        ep[0][1][j*16 + l16][wave*4 + quad] = pd0;
        ep[1][0][j*16 + l16][wave*4 + quad] = ps1;
        ep[1][1][j*16 + l16][wave*4 + quad] = pd1;
    }
    float* mvb = meanV1p + ((size_t)e*B + b)*512;
    #pragma unroll
    for (int r = 0; r < 4; r++){
        float cm0 = acc[0][r] + acc[1][r] + acc[2][r] + acc[3][r];
        float cm1 = acc[4][r] + acc[5][r] + acc[6][r] + acc[7][r];
        for (int off = 8; off; off >>= 1){
            cm0 += __shfl_down(cm0, off, 16);
            cm1 += __shfl_down(cm1, off, 16);
        }
        if (l16 == 0){
            atomicAdd(mvb + (obase + r)*8 + h0, cm0*(1.f/(float)S));
            atomicAdd(mvb + (obase + r)*8 + h1, cm1*(1.f/(float)S));
        }
    }
    __syncthreads();
    {
        int hh = tid >> 7, arr = (tid >> 6) & 1, sl = tid & 63;
        float sum = 0.f;
        #pragma unroll
        for (int i = 0; i < 16; i++) sum += ep[hh][arr][sl][i];
        int n = n0 + sl;
        float* dst = arr ? ed8 : es8;
        dst[(((size_t)e*B + (n >> 10))*S + (n & 1023))*8 + (p*2 + hh)] = sum;
    }
}

// ---------- attn1 gather v2: 2 waves cooperate per (e,b,s) row; split neighbor list ----------
// grid (S, 16), 128 threads. Halves the serial neighbor-loop depth vs 1-wave version.
__global__ __launch_bounds__(128) void attn1_gather_kernel(const unsigned short* __restrict__ htn4,
                                                           const float* __restrict__ es8,
                                                           const float* __restrict__ ed8,
                                                           const short* __restrict__ nbr,
                                                           const int4* __restrict__ nbc,
                                                           const float* __restrict__ meanV1p,
                                                           unsigned short* __restrict__ h1c4){
    __shared__ float wrec[MAXN][8];    // 4 KB: w0..w5, t, pad
    __shared__ float pacc[64][8];      // 2 KB: wave1 partial acc
    __shared__ float pden[2][8];
    int wave = threadIdx.x >> 6, lane = threadIdx.x & 63;
    int s = blockIdx.x;
    int e = blockIdx.y >> 2, b = blockIdx.y & 3;
    int row = b*S + s;
    int4 c = nbc[row];
    int lo = 0, hi = c.x;
    if (e == 1) hi = c.y;
    else if (e == 2){ lo = c.y; hi = c.z; }
    else if (e == 3){ lo = c.z; }
    int nn = hi - lo;
    const float* esp = es8 + (((size_t)e*B + b)*S + s)*8;
    f32x4 es_lo = *(const f32x4*)esp;
    f32x4 es_hi = *(const f32x4*)(esp + 4);
    float esv[6] = {es_lo[0], es_lo[1], es_lo[2], es_lo[3], es_hi[0], es_hi[1]};
    const float* edb = ed8 + ((size_t)e*B + b)*S*8;
    const short* nl = nbr + (size_t)row*MAXN;
    // weight phase: wave w handles neighbor indices [w*64, w*64+64)
    int i = wave*64 + lane;
    float w[6] = {0,0,0,0,0,0};
    if (i < nn){
        int t = nl[lo + i];
        const float* epn = edb + (size_t)t*8;
        f32x4 d0 = *(const f32x4*)epn;
        f32x4 d1 = *(const f32x4*)(epn + 4);
        float edv[6] = {d0[0], d0[1], d0[2], d0[3], d1[0], d1[1]};
        #pragma unroll
        for (int h = 0; h < 6; h++) w[h] = __expf(leaky(esv[h] + edv[h]));
        f32x4 r0 = {w[0], w[1], w[2], w[3]};
        f32x4 r1 = {w[4], w[5], i2f(t), 0.f};
        *(f32x4*)&wrec[i][0] = r0;
        *(f32x4*)&wrec[i][4] = r1;
    }
    // per-wave partial denominators
    #pragma unroll
    for (int h = 0; h < 6; h++){
        float x = w[h];
        for (int o2 = 32; o2; o2 >>= 1) x += __shfl_down(x, o2);
        if (lane == 0) pden[wave][h] = x;
    }
    __syncthreads();
    // gather phase: stride-2 interleave across the 2 waves
    const unsigned short* Vb = htn4 + ((size_t)e*ROWS + b*S)*HHD + lane;
    float acc[6] = {0,0,0,0,0,0};
    #pragma unroll 4
    for (int j = wave; j < nn; j += 2){
        f32x4 r0 = *(const f32x4*)&wrec[j][0];
        f32x4 r1 = *(const f32x4*)&wrec[j][4];
        int t = f2i(r1[2]);
        const unsigned short* vp = Vb + (size_t)t*HHD;
        float v0 = bf2f(vp[0]);
        float v1 = bf2f(vp[64]);
        float v2 = bf2f(vp[128]);
        float v3 = bf2f(vp[192]);
        float v4 = bf2f(vp[256]);
        float v5 = bf2f(vp[320]);
        acc[0] += r0[0]*v0; acc[1] += r0[1]*v1;
        acc[2] += r0[2]*v2; acc[3] += r0[3]*v3;
        acc[4] += r1[0]*v4; acc[5] += r1[1]*v5;
    }
    if (wave == 1){
        f32x4 p0 = {acc[0], acc[1], acc[2], acc[3]};
        f32x4 p1 = {acc[4], acc[5], 0.f, 0.f};
        *(f32x4*)&pacc[lane][0] = p0;
        *(f32x4*)&pacc[lane][4] = p1;
    }
    __syncthreads();
    if (wave == 0){
        unsigned short* outp = h1c4 + ((size_t)e*ROWS + row)*HHD;
        const float* mv = meanV1p + ((size_t)e*B + b)*512 + lane*8;
        #pragma unroll
        for (int h = 0; h < 6; h++){
            float den = pden[0][h] + pden[1][h];
            float v = (nn > 0) ? (acc[h] + pacc[lane][h])/den : mv[h];
            v = v > 0.f ? v : __expf(v) - 1.f;   // ELU
            outp[h*64 + lane] = f2bf(v);
        }
    }
}

// ---------- GEMM2 (h1@W2) + fused f2s/f2d + colmean; 128-wide M-tile ----------
// grid (D/128=2, ROWS/64, 4experts). launch_bounds(256,4) + pipelined K-loop.
__global__ __launch_bounds__(256, 4) void gemm2_kernel(const unsigned short* __restrict__ w2nk,
                                                    const unsigned short* __restrict__ h1c4,
                                                    const float* __restrict__ main_a2s,
                                                    const float* __restrict__ main_a2d,
                                                    const float* __restrict__ dep_a2s,
                                                    const float* __restrict__ dep_a2d,
                                                    unsigned short* __restrict__ h2n4,
                                                    float* __restrict__ f2s4,
                                                    float* __restrict__ f2d4,
                                                    float* __restrict__ meanV2){
    __shared__ float ep[2][2][64][17];     // [m-half][s/d][n][m-chunk]
    int tid = threadIdx.x, wave = tid >> 6, lane = tid & 63;
    int quad = lane >> 4, l16 = lane & 15;
    int e = blockIdx.z;
    int m0 = blockIdx.x*128;
    int n0 = blockIdx.y*64;
    f32x4 z4 = {0.f,0.f,0.f,0.f};
    const unsigned short* arow0 = w2nk + (size_t)e*D*HHD + (size_t)(m0 + wave*16 + l16)*HHD + quad*8;
    const unsigned short* arow1 = arow0 + (size_t)64*HHD;
    const unsigned short* brow[4];
    #pragma unroll
    for (int j = 0; j < 4; j++)
        brow[j] = h1c4 + (size_t)e*ROWS*HHD + (size_t)(n0 + j*16 + l16)*HHD + quad*8;
    f32x4 acc[8] = {z4, z4, z4, z4, z4, z4, z4, z4};
    bf8_t a0F = *(const bf8_t*)(arow0);
    bf8_t a1F = *(const bf8_t*)(arow1);
    bf8_t bF[4];
    #pragma unroll
    for (int j = 0; j < 4; j++) bF[j] = *(const bf8_t*)(brow[j]);
    #pragma unroll
    for (int it = 0; it < HHD/32; it++){
        bf8_t a0C = a0F, a1C = a1F;
        bf8_t bC[4] = {bF[0], bF[1], bF[2], bF[3]};
        if (it + 1 < HHD/32){
            int kn = (it + 1)*32;
            a0F = *(const bf8_t*)(arow0 + kn);
            a1F = *(const bf8_t*)(arow1 + kn);
            #pragma unroll
            for (int j = 0; j < 4; j++) bF[j] = *(const bf8_t*)(brow[j] + kn);
        }
        #pragma unroll
        for (int j = 0; j < 4; j++){
            acc[j]   = __builtin_amdgcn_mfma_f32_16x16x32_bf16(a0C, bC[j], acc[j],   0, 0, 0);
            acc[4+j] = __builtin_amdgcn_mfma_f32_16x16x32_bf16(a1C, bC[j], acc[4+j], 0, 0, 0);
        }
    }
    int b = n0 >> 10;
    int mbase0 = m0 + wave*16 + quad*4;
    int mbase1 = mbase0 + 64;
    #pragma unroll
    for (int j = 0; j < 4; j++){
        int row = n0 + j*16 + l16;
        ushort4 o0, o1;
        o0.x = f2bf(acc[j][0]);   o0.y = f2bf(acc[j][1]);
        o0.z = f2bf(acc[j][2]);   o0.w = f2bf(acc[j][3]);
        o1.x = f2bf(acc[4+j][0]); o1.y = f2bf(acc[4+j][1]);
        o1.z = f2bf(acc[4+j][2]); o1.w = f2bf(acc[4+j][3]);
        *(ushort4*)(h2n4 + ((size_t)e*ROWS + row)*D + mbase0) = o0;
        *(ushort4*)(h2n4 + ((size_t)e*ROWS + row)*D + mbase1) = o1;
    }
    const float* a2sp = (e == 0) ? main_a2s : dep_a2s + (size_t)(e-1)*D;
    const float* a2dp = (e == 0) ? main_a2d : dep_a2d + (size_t)(e-1)*D;
    float s0v[4], d0v[4], s1v[4], d1v[4];
    #pragma unroll
    for (int r = 0; r < 4; r++){
        s0v[r] = a2sp[mbase0 + r]; d0v[r] = a2dp[mbase0 + r];
        s1v[r] = a2sp[mbase1 + r]; d1v[r] = a2dp[mbase1 + r];
    }
    #pragma unroll
    for (int j = 0; j < 4; j++){
        float ps0 = 0.f, pd0 = 0.f, ps1 = 0.f, pd1 = 0.f;
        #pragma unroll
        for (int r = 0; r < 4; r++){
            ps0 += acc[j][r]*s0v[r];   pd0 += acc[j][r]*d0v[r];
            ps1 += acc[4+j][r]*s1v[r]; pd1 += acc[4+j][r]*d1v[r];
        }
        ep[0][0][j*16 + l16][wave*4 + quad] = ps0;
        ep[0][1][j*16 + l16][wave*4 + quad] = pd0;
        ep[1][0][j*16 + l16][wave*4 + quad] = ps1;
        ep[1][1][j*16 + l16][wave*4 + quad] = pd1;
    }
    #pragma unroll
    for (int r = 0; r < 4; r++){
        float cm0 = acc[0][r] + acc[1][r] + acc[2][r] + acc[3][r];
        float cm1 = acc[4][r] + acc[5][r] + acc[6][r] + acc[7][r];
        for (int off = 8; off; off >>= 1){
            cm0 += __shfl_down(cm0, off, 16);
            cm1 += __shfl_down(cm1, off, 16);
        }
        if (l16 == 0){
            atomicAdd(meanV2 + ((size_t)e*B + b)*D + mbase0 + r, cm0*(1.f/(float)S));
            atomicAdd(meanV2 + ((size_t)e*B + b)*D + mbase1 + r, cm1*(1.f/(float)S));
        }
    }
    __syncthreads();
    {
        int hh = tid >> 7, arr = (tid >> 6) & 1, sl = tid & 63;
        float sum = 0.f;
        #pragma unroll
        for (int i = 0; i < 16; i++) sum += ep[hh][arr][sl][i];
        int n = n0 + sl;
        float* dst = arr ? f2d4 : f2s4;
        atomicAdd(dst + (size_t)e*ROWS + n, sum);
    }
}

// ---------- attn2 + blend v2: waves 0,1 split main expert; waves 2,3 split ACTIVE deputies ----------
// The 3 deputy ranges partition [0,c.x); the router-dropped deputy (rmask==0) is skipped entirely.
// Weights are pre-scaled by 1/den so all active deputies accumulate into one register accumulator.
// grid (S, B), 256 threads
__global__ __launch_bounds__(256) void attn2_blend_kernel(const unsigned short* __restrict__ h2n4,
                                                          const float* __restrict__ f2s4,
                                                          const float* __restrict__ f2d4,
                                                          const short* __restrict__ nbr,
                                                          const int4* __restrict__ nbc,
                                                          const float* __restrict__ meanV2,
                                                          const float* __restrict__ gatebuf,
                                                          const float* __restrict__ rmask,
                                                          const float* __restrict__ sumBuf,
                                                          float* __restrict__ outp){
    __shared__ float2 wrec0[MAXN];    // main expert entries
    __shared__ float2 wrec1[MAXN];    // deputy entries (partition of [0,c.x))
    __shared__ float pacc[3][256];    // partial accs of waves 1,2,3
    __shared__ float pden[4][4];      // [wave][expert-slot]
    int wave = threadIdx.x >> 6, lane = threadIdx.x & 63;
    int s = blockIdx.x, b = blockIdx.y;
    int row = b*S + s;
    int4 c = nbc[row];
    float rm0 = rmask[row], rm1 = rmask[ROWS + row], rm2 = rmask[2*ROWS + row];
    const short* nl = nbr + (size_t)row*MAXN;
    // ---- weight phase ----
    if (wave < 2){
        int i = wave*64 + lane;
        float w = 0.f;
        if (i < c.x){
            int t = nl[i];
            float fs = f2s4[row];
            w = __expf(leaky(fs + f2d4[(size_t)b*S + t]));
            float2 r; r.x = w; r.y = i2f(t);
            wrec0[i] = r;
        }
        float dsum = w;
        for (int o2 = 32; o2; o2 >>= 1) dsum += __shfl_down(dsum, o2);
        if (lane == 0) pden[wave][0] = dsum;
    } else {
        int i = (wave - 2)*64 + lane;
        float w = 0.f, d1 = 0.f, d2 = 0.f, d3 = 0.f;
        if (i < c.x){
            int t = nl[i];
            int tag = (i < c.y) ? 1 : ((i < c.z) ? 2 : 3);
            float act = (tag == 1) ? rm0 : ((tag == 2) ? rm1 : rm2);
            if (act != 0.f){
                float fs = f2s4[(size_t)tag*ROWS + row];
                w = __expf(leaky(fs + f2d4[(size_t)tag*ROWS + (size_t)b*S + t]));
            }
            float2 r; r.x = w; r.y = i2f(t);
            wrec1[i] = r;
            if (tag == 1) d1 = w; else if (tag == 2) d2 = w; else d3 = w;
        }
        for (int o2 = 32; o2; o2 >>= 1){
            d1 += __shfl_down(d1, o2);
            d2 += __shfl_down(d2, o2);
            d3 += __shfl_down(d3, o2);
        }
        if (lane == 0){ pden[wave][1] = d1; pden[wave][2] = d2; pden[wave][3] = d3; }
    }
    __syncthreads();
    // ---- gather phase ----
    float acc[4] = {0.f, 0.f, 0.f, 0.f};
    if (wave < 2){
        float inv = 1.f/(pden[0][0] + pden[1][0]);   // c.x >= 1 (self-loop) always
        const unsigned short* V = h2n4 + (size_t)b*S*D;
        #pragma unroll 4
        for (int j = wave; j < c.x; j += 2){
            float2 r = wrec0[j];
            float wv = r.x*inv;
            int t = f2i(r.y);
            const unsigned short* vp = V + (size_t)t*D + lane*4;
            uint2 dv = *(const uint2*)vp;
            acc[0] += wv*blo(dv.x); acc[1] += wv*bhi(dv.x);
            acc[2] += wv*blo(dv.y); acc[3] += wv*bhi(dv.y);
        }
    } else {
        int rlo[3] = {0, c.y, c.z};
        int rhi[3] = {c.y, c.z, c.x};
        float ract[3] = {rm0, rm1, rm2};
        for (int rg = 0; rg < 3; rg++){
            if (ract[rg] == 0.f || rhi[rg] <= rlo[rg]) continue;
            float inv = 1.f/(pden[2][rg+1] + pden[3][rg+1]);
            const unsigned short* V = h2n4 + ((size_t)(rg+1)*ROWS + (size_t)b*S)*D;
            #pragma unroll 4
            for (int j = rlo[rg] + (wave - 2); j < rhi[rg]; j += 2){
                float2 r = wrec1[j];
                float wv = r.x*inv;
                int t = f2i(r.y);
                const unsigned short* vp = V + (size_t)t*D + lane*4;
                uint2 dv = *(const uint2*)vp;
                acc[0] += wv*blo(dv.x); acc[1] += wv*bhi(dv.x);
                acc[2] += wv*blo(dv.y); acc[3] += wv*bhi(dv.y);
            }
        }
    }
    if (wave >= 1){
        #pragma unroll
        for (int q = 0; q < 4; q++) pacc[wave-1][lane*4 + q] = acc[q];
    }
    __syncthreads();
    // ---- combine + blend (wave 0) ----
    if (wave == 0){
        float4 g4 = *(const float4*)(gatebuf + (size_t)row*D + lane*4);
        float dep_mv[4] = {0.f, 0.f, 0.f, 0.f};
        // mean fallback for active deputies with empty neighbor range (uniform attention)
        if (rm0 != 0.f && c.y == 0){
            float4 mv = *(const float4*)(meanV2 + ((size_t)1*B + b)*D + lane*4);
            dep_mv[0] += mv.x; dep_mv[1] += mv.y; dep_mv[2] += mv.z; dep_mv[3] += mv.w;
        }
        if (rm1 != 0.f && c.z == c.y){
            float4 mv = *(const float4*)(meanV2 + ((size_t)2*B + b)*D + lane*4);
            dep_mv[0] += mv.x; dep_mv[1] += mv.y; dep_mv[2] += mv.z; dep_mv[3] += mv.w;
        }
        if (rm2 != 0.f && c.x == c.z){
            float4 mv = *(const float4*)(meanV2 + ((size_t)3*B + b)*D + lane*4);
            dep_mv[0] += mv.x; dep_mv[1] += mv.y; dep_mv[2] += mv.z; dep_mv[3] += mv.w;
        }
        float g[4] = {g4.x, g4.y, g4.z, g4.w};
        float4 o;
        float* op = &o.x;
        #pragma unroll
        for (int q = 0; q < 4; q++){
            int col = lane*4 + q;
            float a0 = acc[q] + pacc[0][col];
            float dep = pacc[1][col] + pacc[2][col] + dep_mv[q];
            op[q] = g[q]*a0 + (1.f - g[q])*dep;
        }
        *(float4*)(outp + (size_t)row*D + lane*4) = o;
    }
    if (blockIdx.x == 0 && blockIdx.y == 0 && threadIdx.x == 0){
        float mc = sumBuf[0] / (float)(ROWS*D);   // filled during gemm1 gate pass
        outp[ROWS*D]     = fabsf(mc - 0.6f)*0.01f;
        outp[ROWS*D + 1] = mc;
    }
}

extern "C" void kernel_launch(void* const* d_in, const int* in_sizes, int n_in,
                              void* d_out, int out_size, void* d_ws, size_t ws_size,
                              hipStream_t stream)
{
    const float* feature  = (const float*)d_in[0];
    const float* adj      = (const float*)d_in[1];
    const float* main_W1  = (const float*)d_in[2];
    const float* main_a1s = (const float*)d_in[3];
    const float* main_a1d = (const float*)d_in[4];
    const float* main_W2  = (const float*)d_in[5];
    const float* main_a2s = (const float*)d_in[6];
    const float* main_a2d = (const float*)d_in[7];
    const float* dep_W1   = (const float*)d_in[8];
    const float* dep_a1s  = (const float*)d_in[9];
    const float* dep_a1d  = (const float*)d_in[10];
    const float* dep_W2   = (const float*)d_in[11];
    const float* dep_a2s  = (const float*)d_in[12];
    const float* dep_a2d  = (const float*)d_in[13];
    const float* router_W = (const float*)d_in[14];
    const float* blend_W  = (const float*)d_in[15];
    const float* blend_b  = (const float*)d_in[16];
    const int*   doc_p    = (const int*)d_in[17];
    const int*   sect_p   = (const int*)d_in[18];

    char* ws = (char*)d_ws;
    size_t off = 0;
    unsigned short* featbf = (unsigned short*)(ws + off); off += (size_t)ROWS*D*2;        // 2 MB
    short*          nbr    = (short*)(ws + off);          off += (size_t)ROWS*MAXN*2;     // 1 MB
    int4*           nbc    = (int4*)(ws + off);           off += (size_t)ROWS*16;         // 64 KB
    unsigned short* w1nk   = (unsigned short*)(ws + off); off += (size_t)4*HHD*D*2;
    unsigned short* w2nk   = (unsigned short*)(ws + off); off += (size_t)4*D*HHD*2;
    unsigned short* bwt    = (unsigned short*)(ws + off); off += (size_t)D*D*2;
    float* es8 = (float*)(ws + off); off += (size_t)4*B*S*8*4;   // 512 KB
    float* ed8 = (float*)(ws + off); off += (size_t)4*B*S*8*4;   // 512 KB
    float* gatebuf = (float*)(ws + off); off += (size_t)ROWS*D*4;                         // 4 MB
    // region A: htn (12 MB)
    unsigned short* htn4 = (unsigned short*)(ws + off); off += (size_t)4*ROWS*HHD*2;
    // region C: h2n4 (8 MB)
    unsigned short* h2n4 = (unsigned short*)(ws + off); off += (size_t)4*ROWS*D*2;
    unsigned short* h1c4 = (unsigned short*)(ws + off); off += (size_t)4*ROWS*HHD*2;      // 12 MB
    // contiguous zero region (NZERO floats):
    float* f2s4    = (float*)(ws + off); off += (size_t)4*ROWS*4;
    float* f2d4    = (float*)(ws + off); off += (size_t)4*ROWS*4;
    float* meanV1p = (float*)(ws + off); off += (size_t)4*B*512*4;
    float* meanV2  = (float*)(ws + off); off += (size_t)4*B*D*4;
    float* sumBuf  = (float*)(ws + off); off += 128;
    float* rmask   = (float*)(ws + off); off += (size_t)NE*ROWS*4;
    float* outp    = (float*)d_out;

    prep_misc_kernel<<<PB_TOTAL, 256, 0, stream>>>(
        feature, adj, main_W1, dep_W1, main_W2, dep_W2, blend_W, router_W,
        doc_p, sect_p, featbf, nbr, nbc, w1nk, w2nk, bwt, f2s4, rmask);

    gemm1_kernel<<<dim3(3, ROWS/64, 5), 256, 0, stream>>>(w1nk, featbf, rmask,
        main_a1s, main_a1d, dep_a1s, dep_a1d, bwt, blend_b,
        htn4, es8, ed8, meanV1p, gatebuf, sumBuf);
    attn1_gather_kernel<<<dim3(S, 16), 128, 0, stream>>>(htn4, es8, ed8, nbr, nbc,
        meanV1p, h1c4);
    gemm2_kernel<<<dim3(D/128, ROWS/64, 4), 256, 0, stream>>>(w2nk, h1c4,
        main_a2s, main_a2d, dep_a2s, dep_a2d, h2n4, f2s4, f2d4, meanV2);
    attn2_blend_kernel<<<dim3(S, B), 256, 0, stream>>>(h2n4, f2s4, f2d4, nbr, nbc,
        meanV2, gatebuf, rmask, sumBuf, outp);
}